// Round 6
// baseline (31.301 us; speedup 1.0000x reference)
//
#include <hip/hip_runtime.h>

#define CP_NUM 16
#define SEGS   16
#define WPB    4            // waves per block; each wave = 2 curves
#define BLK    (WPB * 64)

typedef float f32x4 __attribute__((ext_vector_type(4)));

// Fast reciprocal: v_rcp_f32 (~1 ulp); ample for the 9.25e-2 threshold
// (measured absmax with this math: 1.56e-2).
__device__ __forceinline__ float frcp(float x) { return __builtin_amdgcn_rcpf(x); }

// TWO curves per wave, one per 32-lane half (structure identical to round-5,
// which tied rounds 2/4 at ~27.8 us). ONLY change this round: nontemporal
// float4 stores in the emit phase, to test the L3 dirty-eviction theory
// (isolated A/B; round 3 bundled nt with an unrelated setup rewrite).
__global__ __launch_bounds__(BLK, 8) void spline_poly_kernel(
    const float* __restrict__ cps, float* __restrict__ out, int nb)
{
    __shared__ __align__(16) float4 s_cp [WPB][16];            // 2 curves x 32 floats
    __shared__ __align__(16) float  s_aux[WPB][2][19 * 2];
    __shared__ __align__(16) float  s_t  [WPB][2][20];
    __shared__ __align__(16) float  s_seg[WPB][2][SEGS][12];   // cx[4] cy[4] dt pad[3]

    const int lane = threadIdx.x & 63;
    const int wv   = threadIdx.x >> 6;
    const int half = lane >> 5;          // which curve of the pair
    const int r    = lane & 31;          // role within the half-wave
    const int pw   = blockIdx.x * WPB + wv;     // curve-pair index
    const int base = pw * 2;
    if (base >= nb) return;
    const int ncur = (nb - base < 2) ? (nb - base) : 2;

    // ---- Phase 1: stage 2 curves' control points (16 x float4, coalesced) --
    if (lane < 8 * ncur) {
        s_cp[wv][lane] =
            reinterpret_cast<const float4*>(cps + (size_t)base * (CP_NUM * 2))[lane];
    }
    __builtin_amdgcn_wave_barrier();

    const float* cpw = reinterpret_cast<const float*>(s_cp[wv]) + half * 32;

    // ---- Phase 2: auxiliary points (both halves active, r<19) ----
    // aux[0]=aux_first, aux[1..16]=cps[0..15], aux[17]=cps[0], aux[18]=aux_last
    if (r < 19) {
        const float c0x = cpw[0],  c0y = cpw[1];
        const float c1x = cpw[2],  c1y = cpw[3];
        const float cLx = cpw[30], cLy = cpw[31];
        const float dx01 = c0x - c1x, dy01 = c0y - c1y;
        const float l01   = sqrtf(dx01 * dx01 + dy01 * dy01 + 1e-7f);
        const float dxl = c0x - cLx, dyl = c0y - cLy;     // cc[-1]-cc[-2]
        const float llast = sqrtf(dxl * dxl + dyl * dyl + 1e-7f);
        float ax, ay;
        if (r == 0) {
            const float rr = l01 * frcp(llast);
            ax = c0x - rr * dxl;  ay = c0y - rr * dyl;
        } else if (r <= CP_NUM) {
            ax = cpw[(r - 1) * 2];  ay = cpw[(r - 1) * 2 + 1];
        } else if (r == CP_NUM + 1) {
            ax = c0x;  ay = c0y;
        } else {
            const float rr = llast * frcp(l01);
            ax = c0x + rr * (c1x - c0x);  ay = c0y + rr * (c1y - c0y);
        }
        s_aux[wv][half][r * 2]     = ax;
        s_aux[wv][half][r * 2 + 1] = ay;
    }
    __builtin_amdgcn_wave_barrier();

    // ---- Phase 3: knot increments + half-wave inclusive scan (width 32) ----
    float len = 0.f;
    if (r < 18) {
        const float dx = s_aux[wv][half][(r + 1) * 2]     - s_aux[wv][half][r * 2];
        const float dy = s_aux[wv][half][(r + 1) * 2 + 1] - s_aux[wv][half][r * 2 + 1];
        len = sqrtf(sqrtf(dx * dx + dy * dy));   // (||d||^2)^(1/4)
    }
    #pragma unroll
    for (int d = 1; d < 32; d <<= 1) {
        const float n = __shfl_up(len, d, 32);   // confined to each half-wave
        if (r >= d) len += n;
    }
    if (r == 0) s_t[wv][half][0] = 0.f;
    if (r < 18) s_t[wv][half][r + 1] = len;
    __builtin_amdgcn_wave_barrier();

    // ---- Phase 4: cubic coefficients per segment (r<16, both halves) ----
    if (r < SEGS) {
        const float t0 = s_t[wv][half][r];
        const float t1 = s_t[wv][half][r + 1];
        const float t2 = s_t[wv][half][r + 2];
        const float t3 = s_t[wv][half][r + 3];
        const float A  = t1 - t0, Bk = t2 - t1, C = t3 - t2;
        const float BC = Bk + C;
        const float r10 = frcp(A);
        const float r21 = frcp(Bk);
        const float r32 = frcp(C);
        const float r20 = frcp(A + Bk);
        const float r31 = frcp(BC);

        float* sp = s_seg[wv][half][r];
        #pragma unroll
        for (int d = 0; d < 2; ++d) {   // d=0: x, d=1: y
            const float P0 = s_aux[wv][half][r * 2 + d];
            const float P1 = s_aux[wv][half][r * 2 + 2 + d];
            const float P2 = s_aux[wv][half][r * 2 + 4 + d];
            const float P3 = s_aux[wv][half][r * 2 + 6 + d];
            // Linear pyramid legs: value + slope in s = tv - t1
            const float L1c0 = P1,                        L1c1 = (P1 - P0) * r10;
            const float L2c0 = P1,                        L2c1 = (P2 - P1) * r21;
            const float L3c0 = (BC * P2 - Bk * P3) * r32, L3c1 = (P3 - P2) * r32;
            // Quadratics
            const float Q1c0 = r20 * (Bk * L1c0 + A * L2c0);
            const float Q1c1 = r20 * (Bk * L1c1 - L1c0 + A * L2c1 + L2c0);
            const float Q1c2 = r20 * (L2c1 - L1c1);
            const float Q2c0 = r31 * (BC * L2c0);
            const float Q2c1 = r31 * (BC * L2c1 - L2c0 + L3c0);
            const float Q2c2 = r31 * (L3c1 - L2c1);
            // Cubic: [1,-r21] conv Q1 + [0,r21] conv Q2
            sp[d * 4 + 0] = Q1c0;
            sp[d * 4 + 1] = Q1c1 + r21 * (Q2c0 - Q1c0);
            sp[d * 4 + 2] = Q1c2 + r21 * (Q2c1 - Q1c1);
            sp[d * 4 + 3] = r21 * (Q2c2 - Q1c2);
        }
        sp[8] = Bk;   // t2 - t1: scales u into local parameter s
    }
    __builtin_amdgcn_wave_barrier();

    // ---- Phase 5: emit 2 curves x 512 float4, coalesced NONTEMPORAL ----
    // For curve cv, float4 f = lane + 64*j: f&31 == r (loop-invariant),
    // seg = 2*j + half. Coeff reads are half-wave LDS broadcasts.
    const float q0 = (float)(r * 2)     * (1.f / 63.f);
    const float q1 = (float)(r * 2 + 1) * (1.f / 63.f);
    #pragma unroll
    for (int cv = 0; cv < 2; ++cv) {
        if (base + cv >= nb) break;
        f32x4* outw = reinterpret_cast<f32x4*>(out + (size_t)(base + cv) * (SEGS * 64 * 2));
        #pragma unroll
        for (int j = 0; j < 8; ++j) {
            const float* sp = s_seg[wv][cv][2 * j + half];
            const f32x4 cx = *reinterpret_cast<const f32x4*>(sp);
            const f32x4 cy = *reinterpret_cast<const f32x4*>(sp + 4);
            const float dt = sp[8];
            const float s0 = dt * q0;
            const float s1 = dt * q1;
            f32x4 o;
            o.x = ((cx.w * s0 + cx.z) * s0 + cx.y) * s0 + cx.x;
            o.y = ((cy.w * s0 + cy.z) * s0 + cy.y) * s0 + cy.x;
            o.z = ((cx.w * s1 + cx.z) * s1 + cx.y) * s1 + cx.x;
            o.w = ((cy.w * s1 + cy.z) * s1 + cy.y) * s1 + cy.x;
            __builtin_nontemporal_store(o, &outw[lane + 64 * j]);
        }
    }
}

extern "C" void kernel_launch(void* const* d_in, const int* in_sizes, int n_in,
                              void* d_out, int out_size, void* d_ws, size_t ws_size,
                              hipStream_t stream) {
    const float* cps = (const float*)d_in[0];
    float* out = (float*)d_out;
    const int B = in_sizes[0] / (CP_NUM * 2);          // 16384
    const int npairs = (B + 1) / 2;                    // 8192
    const int grid = (npairs + WPB - 1) / WPB;         // 2048
    spline_poly_kernel<<<grid, BLK, 0, stream>>>(cps, out, B);
}

// Round 7
// 27.748 us; speedup vs baseline: 1.1280x; 1.1280x over previous
//
#include <hip/hip_runtime.h>

#define CP_NUM 16
#define SEGS   16
#define WPB    4            // waves (= curves) per block
#define BLK    (WPB * 64)

typedef float f32x4 __attribute__((ext_vector_type(4)));

// FINAL (revert to round-2 best, 27.74 us). Roofline: two-point fit of
// {this kernel: 134.2 MB @ 27.8 us} and {harness fill: 512 MB @ 79.5 us}
// gives identical machine params (7.3 TB/s marginal write BW, 9.5 us fixed
// dispatch cost) -> zero headroom vs the platform's own memset.
// A/B history: frcp (neutral), 2-curves/wave (neutral), nontemporal stores
// (-12%, L2/L3 write-combining matters), shuffle-setup (-10%).
__global__ __launch_bounds__(BLK) void spline_poly_kernel(
    const float* __restrict__ cps, float* __restrict__ out, int nb)
{
    __shared__ __align__(16) float s_cp [WPB][CP_NUM * 2];
    __shared__ __align__(16) float s_aux[WPB][19 * 2];
    __shared__ __align__(16) float s_t  [WPB][20];
    __shared__ __align__(16) float s_seg[WPB][SEGS][12]; // cx[4] cy[4] dt pad[3]

    const int lane = threadIdx.x & 63;
    const int wv   = threadIdx.x >> 6;
    const int b    = blockIdx.x * WPB + wv;
    if (b >= nb) return;

    // ---- Phase 1: stage control points (8 x float4, coalesced) ----
    if (lane < 8) {
        reinterpret_cast<float4*>(s_cp[wv])[lane] =
            reinterpret_cast<const float4*>(cps + (size_t)b * (CP_NUM * 2))[lane];
    }
    __builtin_amdgcn_wave_barrier();

    // ---- Phase 2: auxiliary points ----
    // aux[0]=aux_first, aux[1..16]=cps[0..15], aux[17]=cps[0], aux[18]=aux_last
    if (lane < 19) {
        const float c0x = s_cp[wv][0],  c0y = s_cp[wv][1];
        const float c1x = s_cp[wv][2],  c1y = s_cp[wv][3];
        const float cLx = s_cp[wv][30], cLy = s_cp[wv][31];
        const float dx01 = c0x - c1x, dy01 = c0y - c1y;
        const float l01   = sqrtf(dx01 * dx01 + dy01 * dy01 + 1e-7f);
        const float dxl = c0x - cLx, dyl = c0y - cLy;     // cc[-1]-cc[-2]
        const float llast = sqrtf(dxl * dxl + dyl * dyl + 1e-7f);
        float ax, ay;
        if (lane == 0) {
            const float r = l01 / llast;
            ax = c0x - r * dxl;  ay = c0y - r * dyl;
        } else if (lane <= CP_NUM) {
            ax = s_cp[wv][(lane - 1) * 2];  ay = s_cp[wv][(lane - 1) * 2 + 1];
        } else if (lane == CP_NUM + 1) {
            ax = c0x;  ay = c0y;
        } else {
            const float r = llast / l01;
            ax = c0x + r * (c1x - c0x);  ay = c0y + r * (c1y - c0y);
        }
        s_aux[wv][lane * 2]     = ax;
        s_aux[wv][lane * 2 + 1] = ay;
    }
    __builtin_amdgcn_wave_barrier();

    // ---- Phase 3: knot increments + wave inclusive scan ----
    float len = 0.f;
    if (lane < 18) {
        const float dx = s_aux[wv][(lane + 1) * 2]     - s_aux[wv][lane * 2];
        const float dy = s_aux[wv][(lane + 1) * 2 + 1] - s_aux[wv][lane * 2 + 1];
        len = sqrtf(sqrtf(dx * dx + dy * dy));   // (||d||^2)^(1/4)
    }
    #pragma unroll
    for (int d = 1; d < 32; d <<= 1) {
        const float n = __shfl_up(len, d);
        if (lane >= d) len += n;
    }
    if (lane == 0) s_t[wv][0] = 0.f;
    if (lane < 18) s_t[wv][lane + 1] = len;
    __builtin_amdgcn_wave_barrier();

    // ---- Phase 4: cubic coefficients per segment (lanes 0..15) ----
    if (lane < SEGS) {
        const float t0 = s_t[wv][lane];
        const float t1 = s_t[wv][lane + 1];
        const float t2 = s_t[wv][lane + 2];
        const float t3 = s_t[wv][lane + 3];
        const float A  = t1 - t0, Bk = t2 - t1, C = t3 - t2;
        const float BC = Bk + C;
        const float r10 = 1.f / A;
        const float r21 = 1.f / Bk;
        const float r32 = 1.f / C;
        const float r20 = 1.f / (A + Bk);
        const float r31 = 1.f / BC;

        float* sp = s_seg[wv][lane];
        #pragma unroll
        for (int d = 0; d < 2; ++d) {   // d=0: x, d=1: y
            const float P0 = s_aux[wv][lane * 2 + d];
            const float P1 = s_aux[wv][lane * 2 + 2 + d];
            const float P2 = s_aux[wv][lane * 2 + 4 + d];
            const float P3 = s_aux[wv][lane * 2 + 6 + d];
            // Linear pyramid legs: value + slope in s = tv - t1
            const float L1c0 = P1,                        L1c1 = (P1 - P0) * r10;
            const float L2c0 = P1,                        L2c1 = (P2 - P1) * r21;
            const float L3c0 = (BC * P2 - Bk * P3) * r32, L3c1 = (P3 - P2) * r32;
            // Quadratics
            const float Q1c0 = r20 * (Bk * L1c0 + A * L2c0);
            const float Q1c1 = r20 * (Bk * L1c1 - L1c0 + A * L2c1 + L2c0);
            const float Q1c2 = r20 * (L2c1 - L1c1);
            const float Q2c0 = r31 * (BC * L2c0);
            const float Q2c1 = r31 * (BC * L2c1 - L2c0 + L3c0);
            const float Q2c2 = r31 * (L3c1 - L2c1);
            // Cubic: [1,-r21] conv Q1 + [0,r21] conv Q2
            sp[d * 4 + 0] = Q1c0;
            sp[d * 4 + 1] = Q1c1 + r21 * (Q2c0 - Q1c0);
            sp[d * 4 + 2] = Q1c2 + r21 * (Q2c1 - Q1c1);
            sp[d * 4 + 3] = r21 * (Q2c2 - Q1c2);
        }
        sp[8] = Bk;   // t2 - t1: scales u into local parameter s
    }
    __builtin_amdgcn_wave_barrier();

    // ---- Phase 5: emit 1024 points = 512 float4, coalesced ----
    // f = lane + 64*i: f&31 == lane&31 (loop-invariant), seg = 2*i + (lane>=32).
    f32x4* outw = reinterpret_cast<f32x4*>(out + (size_t)b * (SEGS * 64 * 2));
    const int   hi = lane >> 5;
    const float q0 = (float)((lane & 31) * 2)     * (1.f / 63.f);
    const float q1 = (float)((lane & 31) * 2 + 1) * (1.f / 63.f);
    #pragma unroll
    for (int i = 0; i < 8; ++i) {
        const float* sp = s_seg[wv][2 * i + hi];
        const f32x4 cx = *reinterpret_cast<const f32x4*>(sp);
        const f32x4 cy = *reinterpret_cast<const f32x4*>(sp + 4);
        const float dt = sp[8];
        const float s0 = dt * q0;
        const float s1 = dt * q1;
        f32x4 o;
        o.x = ((cx.w * s0 + cx.z) * s0 + cx.y) * s0 + cx.x;
        o.y = ((cy.w * s0 + cy.z) * s0 + cy.y) * s0 + cy.x;
        o.z = ((cx.w * s1 + cx.z) * s1 + cx.y) * s1 + cx.x;
        o.w = ((cy.w * s1 + cy.z) * s1 + cy.y) * s1 + cy.x;
        outw[lane + 64 * i] = o;
    }
}

extern "C" void kernel_launch(void* const* d_in, const int* in_sizes, int n_in,
                              void* d_out, int out_size, void* d_ws, size_t ws_size,
                              hipStream_t stream) {
    const float* cps = (const float*)d_in[0];
    float* out = (float*)d_out;
    const int B = in_sizes[0] / (CP_NUM * 2);          // 16384
    const int grid = (B + WPB - 1) / WPB;              // 4096
    spline_poly_kernel<<<grid, BLK, 0, stream>>>(cps, out, B);
}